// Round 9
// baseline (1409.608 us; speedup 1.0000x reference)
//
#include <hip/hip_runtime.h>
#include <hip/hip_bf16.h>

#define NB    131072
#define EPB   8      // batch elements per block
#define NTILE 6      // M-tiles: 2 tokens x 8 elems = 16 rows
#define SEQP  12     // 11 tokens + 1 pad (pad = cls copy, finite)
#define SXW   36     // sX row stride (f32)
#define SQW2  66     // sQ row stride (u32): q/ctx raw f32 [0..31], k bf16 u16[64..95], v bf16 u16[96..127]
                     // FFN phase: h bf16 occupies u16 cols [0..127] of the same row

// ws layout (u16 units), per transformer block tb (stride WS_U16_PER_TB):
//   qkv hi @0      [6][64][8]   qkv lo @3072
//   wo  hi @6144   [2][64][8]   wo  lo @7168
//   w1  hi @8192   [8][64][8]   w1  lo @12288
//   w2  hi @16384  [4][2][64][8] w2 lo @20480
#define WS_U16_PER_TB 24576
#define WS_REQ_BYTES  (2 * WS_U16_PER_TB * 2)   // 98304 B

typedef short    bf16x8 __attribute__((ext_vector_type(8)));
typedef float    f32x4  __attribute__((ext_vector_type(4)));
typedef unsigned short u16;

struct Params {
  const float *x, *w_feat, *b_feat, *cls;
  const float *in_w[2], *in_b[2], *out_w[2], *out_b[2];
  const float *ln_a_g[2], *ln_a_b[2];
  const float *w1[2], *b1[2], *w2[2], *b2[2];
  const float *ln_b_g[2], *ln_b_b[2];
  const float *clf_w, *clf_b;
  float *out;
};

__device__ __forceinline__ float bf2f(u16 h){ return __uint_as_float(((unsigned)h)<<16); }
__device__ __forceinline__ u16 f2bf(float f){
  unsigned u = __float_as_uint(f);
  u += 0x7fffu + ((u>>16)&1u);          // RNE
  return (u16)(u>>16);
}
// truncation split: a ~= hi + lo, residual <= 2^-16 |a|
__device__ __forceinline__ void split8t(const float* p, bf16x8& hi, bf16x8& lo){
  #pragma unroll
  for (int j = 0; j < 8; ++j) {
    float a = p[j];
    unsigned u = __float_as_uint(a);
    hi[j] = (short)(u >> 16);
    float r = a - __uint_as_float(u & 0xffff0000u);
    lo[j] = (short)(__float_as_uint(r) >> 16);
  }
}
// RNE split (weights fallback path only)
__device__ __forceinline__ void split8(const float* p, bf16x8& hi, bf16x8& lo){
  #pragma unroll
  for (int j = 0; j < 8; ++j) {
    float a = p[j];
    u16 h = f2bf(a);
    hi[j] = (short)h;
    lo[j] = (short)f2bf(a - bf2f(h));
  }
}
// split-precision MFMA: acc += A*B, A=ah+al, B=bh+bl (drops al*bl ~ 2^-17)
__device__ __forceinline__ f32x4 mfma3(bf16x8 ah, bf16x8 al, bf16x8 bh, bf16x8 bl, f32x4 acc){
  acc = __builtin_amdgcn_mfma_f32_16x16x32_bf16(ah, bl, acc, 0,0,0);
  acc = __builtin_amdgcn_mfma_f32_16x16x32_bf16(al, bh, acc, 0,0,0);
  acc = __builtin_amdgcn_mfma_f32_16x16x32_bf16(ah, bh, acc, 0,0,0);
  return acc;
}
// A exact bf16, B split
__device__ __forceinline__ f32x4 mfma2(bf16x8 a, bf16x8 bh, bf16x8 bl, f32x4 acc){
  acc = __builtin_amdgcn_mfma_f32_16x16x32_bf16(a, bl, acc, 0,0,0);
  acc = __builtin_amdgcn_mfma_f32_16x16x32_bf16(a, bh, acc, 0,0,0);
  return acc;
}
__device__ __forceinline__ bf16x8 ld8(const u16* p){ return *reinterpret_cast<const bf16x8*>(p); }
// sigma-form GELU: v*sigmoid(2y) == 0.5v(1+tanh(y)) exactly (same math as tanh form, fewer ops)
__device__ __forceinline__ float gelu_fast(float v){
  float v2 = v*v;
  float t  = fmaf(0.044715f, v2, 1.0f);
  float u  = -1.5957691216057308f * v;          // -2 * 0.7978845608
  float e  = __expf(u * t);                     // exp(-2y)
  return v * __builtin_amdgcn_rcpf(1.f + e);
}
// paired RNE f32->bf16 (v_cvt_pk_bf16_f32 path)
__device__ __forceinline__ void cvt2(float a, float b, u16& oa, u16& ob){
  __hip_bfloat162 p = __float22bfloat162_rn(float2{a, b});
  oa = *reinterpret_cast<u16*>(&p.x);
  ob = *reinterpret_cast<u16*>(&p.y);
}

// ---------- prep: pre-split weights into per-lane B-fragment layout ----------
__global__ void OptimusPrime_prep(Params P, u16* ws)
{
  const int tb = blockIdx.x;
  u16* b = ws + tb * WS_U16_PER_TB;
  for (int idx = threadIdx.x; idx < 12288; idx += 256) {
    float v; int hiOff, loOff;
    if (idx < 3072) {                       // qkv  [6][64][8], K=32
      int nt = idx >> 9, lane = (idx >> 3) & 63, j = idx & 7;
      v = P.in_w[tb][(nt*16 + (lane&15))*32 + (lane>>4)*8 + j];
      hiOff = idx; loOff = 3072 + idx;
    } else if (idx < 4096) {                // wo   [2][64][8], K=32
      int m = idx - 3072;
      int nt = m >> 9, lane = (m >> 3) & 63, j = m & 7;
      v = P.out_w[tb][(nt*16 + (lane&15))*32 + (lane>>4)*8 + j];
      hiOff = 6144 + m; loOff = 7168 + m;
    } else if (idx < 8192) {                // w1   [8][64][8], K=32
      int m = idx - 4096;
      int nt = m >> 9, lane = (m >> 3) & 63, j = m & 7;
      v = P.w1[tb][(nt*16 + (lane&15))*32 + (lane>>4)*8 + j];
      hiOff = 8192 + m; loOff = 12288 + m;
    } else {                                // w2   [4][2][64][8], K=128
      int m = idx - 8192;
      int kt = m >> 10, nt = (m >> 9) & 1, lane = (m >> 3) & 63, j = m & 7;
      v = P.w2[tb][(nt*16 + (lane&15))*128 + kt*32 + (lane>>4)*8 + j];
      hiOff = 16384 + m; loOff = 20480 + m;
    }
    u16 h = f2bf(v);
    b[hiOff] = h;
    b[loOff] = f2bf(v - bf2f(h));
  }
}

// MFMA 16x16x32 bf16 layouts:
//   A-frag: a[j] = A[m=lane&15][k=(lane>>4)*8+j]
//   B-frag: b[j] = B[k=(lane>>4)*8+j][n=lane&15]
//   C/D   : acc[r] = C[row=(lane>>4)*4+r][col=lane&15]
// M-tile t covers rows m in [0,16): token s = 2t + (m>>3), elem e = m&7.

template<bool WS>
__global__ __launch_bounds__(256, 3)   // 3 waves/EU ~168 unified VGPR cap (r7: ~190 live spills; r8: sub-passes fit)
void OptimusPrime_kernel(Params P, const u16* __restrict__ ws)
{
  __shared__ float    sX[SEQP][EPB][SXW];   // 13824 B : residual stream (f32)
  __shared__ unsigned sQ[SEQP][EPB][SQW2];  // 25344 B : raw f32 q/ctx + bf16 k,v ; FFN h bf16

  const int tid  = threadIdx.x;
  const int w    = tid >> 6;
  const int lane = tid & 63;
  const int quad = lane >> 4;
  const int l16  = lane & 15;
  const int kq   = quad * 8;
  const int base = blockIdx.x * EPB;

  const int sA  = (l16 >> 3);
  const int eA  = (l16 & 7);
  const int sC  = (quad >> 1);
  const int eC0 = (quad & 1) * 4;

  // ---------- embed ----------
  for (int i = tid; i < SEQP*EPB*32; i += 256) {
    int d = i & 31, e = (i >> 5) & 7, s = i >> 8;
    float v;
    if (s == 0 || s == 11) v = P.cls[d];
    else v = P.x[(base+e)*10 + (s-1)] * P.w_feat[(s-1)*32 + d] + P.b_feat[(s-1)*32 + d];
    sX[s][e][d] = v;
  }
  __syncthreads();

  for (int tb = 0; tb < 2; ++tb) {
    const u16* wsb = WS ? (ws + tb * WS_U16_PER_TB) : nullptr;

    // ---------- P1: QKV projection ----------
    {
      bf16x8 bh[6], bl[6]; float bias[6];
      #pragma unroll
      for (int nt = 0; nt < 6; ++nt) {
        if (WS) {
          bh[nt] = ld8(wsb + (nt*64 + lane)*8);
          bl[nt] = ld8(wsb + 3072 + (nt*64 + lane)*8);
        } else {
          split8(P.in_w[tb] + (nt*16 + l16)*32 + kq, bh[nt], bl[nt]);
        }
        bias[nt] = P.in_b[tb][nt*16 + l16];
      }
      for (int t = w; t < NTILE; t += 4) {
        bf16x8 ah, al; split8t(&sX[2*t + sA][eA][kq], ah, al);
        // q (nt 0,1): raw f32
        #pragma unroll
        for (int nt = 0; nt < 2; ++nt) {
          f32x4 acc = {0.f,0.f,0.f,0.f};
          acc = mfma3(ah, al, bh[nt], bl[nt], acc);
          #pragma unroll
          for (int r = 0; r < 4; ++r)
            ((float*)&sQ[2*t + sC][eC0 + r][0])[nt*16 + l16] = acc[r] + bias[nt];
        }
        // k (nt 2,3): paired bf16 convert
        {
          f32x4 a2 = {0.f,0.f,0.f,0.f}, a3 = {0.f,0.f,0.f,0.f};
          a2 = mfma3(ah, al, bh[2], bl[2], a2);
          a3 = mfma3(ah, al, bh[3], bl[3], a3);
          #pragma unroll
          for (int r = 0; r < 4; ++r) {
            u16* row = (u16*)&sQ[2*t + sC][eC0 + r][0];
            cvt2(a2[r] + bias[2], a3[r] + bias[3], row[64 + l16], row[80 + l16]);
          }
        }
        // v (nt 4,5): paired bf16 convert
        {
          f32x4 a4 = {0.f,0.f,0.f,0.f}, a5 = {0.f,0.f,0.f,0.f};
          a4 = mfma3(ah, al, bh[4], bl[4], a4);
          a5 = mfma3(ah, al, bh[5], bl[5], a5);
          #pragma unroll
          for (int r = 0; r < 4; ++r) {
            u16* row = (u16*)&sQ[2*t + sC][eC0 + r][0];
            cvt2(a4[r] + bias[4], a5[r] + bias[5], row[96 + l16], row[112 + l16]);
          }
        }
      }
    }
    __syncthreads();

    // ---------- attention: single pass, dual-qi per thread ----------
    {
      const int e = tid >> 5, hh = (tid >> 3) & 3, qs = tid & 7;
      const int qi1 = qs, qi2 = qs + 8;
      const int qi2r = (qi2 < SEQP) ? qi2 : 11;   // clamped read row (pad, finite)
      const float* q1p = (const float*)&sQ[qi1][e][0] + hh*8;
      const float* q2p = (const float*)&sQ[qi2r][e][0] + hh*8;
      float q1f[8], q2f[8];
      #pragma unroll
      for (int j = 0; j < 8; ++j) {
        q1f[j] = q1p[j] * 0.35355339059f;   // 1/sqrt(8)
        q2f[j] = q2p[j] * 0.35355339059f;
      }
      float sc1[11], sc2[11], l1 = 0.f, l2 = 0.f;
      #pragma unroll
      for (int ki = 0; ki < 11; ++ki) {
        bf16x8 kv = ld8((const u16*)&sQ[ki][e][0] + 64 + hh*8);
        float s1 = 0.f, s2 = 0.f;
        #pragma unroll
        for (int j = 0; j < 8; ++j) {
          float kf = bf2f((u16)kv[j]);
          s1 = fmaf(q1f[j], kf, s1);
          s2 = fmaf(q2f[j], kf, s2);
        }
        sc1[ki] = __expf(s1); l1 += sc1[ki];   // scores O(1): no max-subtraction
        sc2[ki] = __expf(s2); l2 += sc2[ki];
      }
      float inv1 = __builtin_amdgcn_rcpf(l1);
      float inv2 = __builtin_amdgcn_rcpf(l2);
      float cx1[8] = {0,0,0,0,0,0,0,0}, cx2[8] = {0,0,0,0,0,0,0,0};
      #pragma unroll
      for (int ki = 0; ki < 11; ++ki) {
        bf16x8 vv = ld8((const u16*)&sQ[ki][e][0] + 96 + hh*8);
        float p1 = sc1[ki], p2 = sc2[ki];
        #pragma unroll
        for (int j = 0; j < 8; ++j) {
          float vf = bf2f((u16)vv[j]);
          cx1[j] = fmaf(p1, vf, cx1[j]);
          cx2[j] = fmaf(p2, vf, cx2[j]);
        }
      }
      float* w1p = (float*)&sQ[qi1][e][0] + hh*8;
      #pragma unroll
      for (int j = 0; j < 8; ++j) w1p[j] = cx1[j] * inv1;     // ctx -> q slot, raw f32
      if (qi2 < 11) {
        float* w2p = (float*)&sQ[qi2][e][0] + hh*8;
        #pragma unroll
        for (int j = 0; j < 8; ++j) w2p[j] = cx2[j] * inv2;
      }
    }
    __syncthreads();

    // ---------- P3a: out-proj + LN_a (only wo live) ----------
    {
      bf16x8 woh[2], wol[2]; float ob[2], lag[2], lab[2];
      #pragma unroll
      for (int nt = 0; nt < 2; ++nt) {
        if (WS) {
          woh[nt] = ld8(wsb + 6144 + (nt*64 + lane)*8);
          wol[nt] = ld8(wsb + 7168 + (nt*64 + lane)*8);
        } else {
          split8(P.out_w[tb] + (nt*16 + l16)*32 + kq, woh[nt], wol[nt]);
        }
        ob[nt]  = P.out_b[tb][nt*16 + l16];
        lag[nt] = P.ln_a_g[tb][nt*16 + l16]; lab[nt] = P.ln_a_b[tb][nt*16 + l16];
      }
      for (int t = w; t < NTILE; t += 4) {
        bf16x8 ah, al; split8t((const float*)&sQ[2*t + sA][eA][0] + kq, ah, al);  // ctx raw f32
        float tt[2][4];
        #pragma unroll
        for (int nt = 0; nt < 2; ++nt) {
          f32x4 acc = {0.f,0.f,0.f,0.f};
          acc = mfma3(ah, al, woh[nt], wol[nt], acc);
          #pragma unroll
          for (int r = 0; r < 4; ++r)
            tt[nt][r] = acc[r] + ob[nt] + sX[2*t + sC][eC0 + r][nt*16 + l16];  // + residual
        }
        #pragma unroll
        for (int r = 0; r < 4; ++r) {
          float s1 = tt[0][r] + tt[1][r];
          float s2 = tt[0][r]*tt[0][r] + tt[1][r]*tt[1][r];
          #pragma unroll
          for (int mk = 1; mk < 16; mk <<= 1) { s1 += __shfl_xor(s1, mk); s2 += __shfl_xor(s2, mk); }
          float mu  = s1 * (1.f/32.f);
          float var = fmaxf(s2 * (1.f/32.f) - mu*mu, 0.f);
          float rs  = rsqrtf(var + 1e-5f);
          #pragma unroll
          for (int nt = 0; nt < 2; ++nt) {
            float y = (tt[nt][r] - mu)*rs*lag[nt] + lab[nt];
            sX[2*t + sC][eC0 + r][nt*16 + l16] = y;
          }
        }
      }
    }
    __builtin_amdgcn_sched_barrier(0);

    // ---------- P3b: FFN1 + GELU -> h bf16 (only w1 live) ----------
    {
      bf16x8 w1h[8], w1l[8]; float b1v[8];
      #pragma unroll
      for (int f8 = 0; f8 < 8; ++f8) {
        if (WS) {
          w1h[f8] = ld8(wsb + 8192  + (f8*64 + lane)*8);
          w1l[f8] = ld8(wsb + 12288 + (f8*64 + lane)*8);
        } else {
          split8(P.w1[tb] + (f8*16 + l16)*32 + kq, w1h[f8], w1l[f8]);
        }
        b1v[f8] = P.b1[tb][f8*16 + l16];
      }
      for (int t = w; t < NTILE; t += 4) {
        bf16x8 xh, xl; split8t(&sX[2*t + sA][eA][kq], xh, xl);
        #pragma unroll
        for (int fp = 0; fp < 4; ++fp) {
          int f0 = 2*fp, f1 = 2*fp + 1;
          f32x4 a0 = {0.f,0.f,0.f,0.f}, a1 = {0.f,0.f,0.f,0.f};
          a0 = mfma3(xh, xl, w1h[f0], w1l[f0], a0);
          a1 = mfma3(xh, xl, w1h[f1], w1l[f1], a1);
          #pragma unroll
          for (int r = 0; r < 4; ++r) {
            float g0 = gelu_fast(a0[r] + b1v[f0]);
            float g1 = gelu_fast(a1[r] + b1v[f1]);
            u16* row = (u16*)&sQ[2*t + sC][eC0 + r][0];
            cvt2(g0, g1, row[f0*16 + l16], row[f1*16 + l16]);
          }
        }
      }
    }
    __builtin_amdgcn_sched_barrier(0);

    // ---------- P3c: FFN2 + residual + LN_b (only w2 live) ----------
    {
      bf16x8 w2h[4][2], w2l[4][2]; float b2v[2], lbg[2], lbb[2];
      #pragma unroll
      for (int kt = 0; kt < 4; ++kt)
        #pragma unroll
        for (int nt = 0; nt < 2; ++nt) {
          if (WS) {
            w2h[kt][nt] = ld8(wsb + 16384 + ((kt*2 + nt)*64 + lane)*8);
            w2l[kt][nt] = ld8(wsb + 20480 + ((kt*2 + nt)*64 + lane)*8);
          } else {
            split8(P.w2[tb] + (nt*16 + l16)*128 + kt*32 + kq, w2h[kt][nt], w2l[kt][nt]);
          }
        }
      #pragma unroll
      for (int nt = 0; nt < 2; ++nt) {
        b2v[nt] = P.b2[tb][nt*16 + l16];
        lbg[nt] = P.ln_b_g[tb][nt*16 + l16]; lbb[nt] = P.ln_b_b[tb][nt*16 + l16];
      }
      for (int t = w; t < NTILE; t += 4) {
        f32x4 ca0 = {0.f,0.f,0.f,0.f}, ca1 = {0.f,0.f,0.f,0.f};
        #pragma unroll
        for (int kt = 0; kt < 4; ++kt) {
          bf16x8 hf = ld8((const u16*)&sQ[2*t + sA][eA][0] + kt*32 + kq);
          ca0 = mfma2(hf, w2h[kt][0], w2l[kt][0], ca0);
          ca1 = mfma2(hf, w2h[kt][1], w2l[kt][1], ca1);
        }
        float tt[2][4];
        #pragma unroll
        for (int nt = 0; nt < 2; ++nt) {
          f32x4 ca = nt ? ca1 : ca0;
          #pragma unroll
          for (int r = 0; r < 4; ++r)
            tt[nt][r] = ca[r] + b2v[nt] + sX[2*t + sC][eC0 + r][nt*16 + l16];  // + residual
        }
        #pragma unroll
        for (int r = 0; r < 4; ++r) {
          float s1 = tt[0][r] + tt[1][r];
          float s2 = tt[0][r]*tt[0][r] + tt[1][r]*tt[1][r];
          #pragma unroll
          for (int mk = 1; mk < 16; mk <<= 1) { s1 += __shfl_xor(s1, mk); s2 += __shfl_xor(s2, mk); }
          float mu  = s1 * (1.f/32.f);
          float var = fmaxf(s2 * (1.f/32.f) - mu*mu, 0.f);
          float rs  = rsqrtf(var + 1e-5f);
          #pragma unroll
          for (int nt = 0; nt < 2; ++nt) {
            float y = (tt[nt][r] - mu)*rs*lbg[nt] + lbb[nt];
            sX[2*t + sC][eC0 + r][nt*16 + l16] = y;
          }
        }
      }
    }
    // no end-of-layer barrier: next P1 / classifier touch only tiles this wave owns
    // (P3c writes sX C-rows of tile t; next P1 reads A-rows of same tile t, same wave)
  }

  // ---------- classifier: out[b] = sX[0][e][:] . clf_w + clf_b ----------
  // sX token-0 rows 0..7 are tile 0 = wave 0's P3c output (same wave, LDS in-order)
  if (w == 0) {
    int e = lane >> 3, dq = lane & 7;
    float p = 0.f;
    #pragma unroll
    for (int j = 0; j < 4; ++j)
      p += sX[0][e][dq*4 + j] * P.clf_w[dq*4 + j];
    p += __shfl_xor(p, 1);
    p += __shfl_xor(p, 2);
    p += __shfl_xor(p, 4);
    if (dq == 0)
      P.out[base + e] = p + P.clf_b[0];
  }
}

extern "C" void kernel_launch(void* const* d_in, const int* in_sizes, int n_in,
                              void* d_out, int out_size, void* d_ws, size_t ws_size,
                              hipStream_t stream)
{
  Params P;
  P.x        = (const float*)d_in[0];
  P.w_feat   = (const float*)d_in[1];
  P.b_feat   = (const float*)d_in[2];
  P.cls      = (const float*)d_in[3];
  P.in_w[0]  = (const float*)d_in[4];   P.in_b[0]  = (const float*)d_in[5];
  P.out_w[0] = (const float*)d_in[6];   P.out_b[0] = (const float*)d_in[7];
  P.ln_a_g[0]= (const float*)d_in[8];   P.ln_a_b[0]= (const float*)d_in[9];
  P.w1[0]    = (const float*)d_in[10];  P.b1[0]    = (const float*)d_in[11];
  P.w2[0]    = (const float*)d_in[12];  P.b2[0]    = (const float*)d_in[13];
  P.ln_b_g[0]= (const float*)d_in[14];  P.ln_b_b[0]= (const float*)d_in[15];
  P.in_w[1]  = (const float*)d_in[16];  P.in_b[1]  = (const float*)d_in[17];
  P.out_w[1] = (const float*)d_in[18];  P.out_b[1] = (const float*)d_in[19];
  P.ln_a_g[1]= (const float*)d_in[20];  P.ln_a_b[1]= (const float*)d_in[21];
  P.w1[1]    = (const float*)d_in[22];  P.b1[1]    = (const float*)d_in[23];
  P.w2[1]    = (const float*)d_in[24];  P.b2[1]    = (const float*)d_in[25];
  P.ln_b_g[1]= (const float*)d_in[26];  P.ln_b_b[1]= (const float*)d_in[27];
  P.clf_w    = (const float*)d_in[28];  P.clf_b    = (const float*)d_in[29];
  P.out      = (float*)d_out;

  dim3 grid(NB / EPB), block(256);
  if (ws_size >= (size_t)WS_REQ_BYTES) {
    u16* ws = (u16*)d_ws;
    hipLaunchKernelGGL(OptimusPrime_prep, dim3(2), dim3(256), 0, stream, P, ws);
    hipLaunchKernelGGL(OptimusPrime_kernel<true>, grid, block, 0, stream, P, (const u16*)ws);
  } else {
    hipLaunchKernelGGL(OptimusPrime_kernel<false>, grid, block, 0, stream, P, (const u16*)nullptr);
  }
}

// Round 10
// 995.673 us; speedup vs baseline: 1.4157x; 1.4157x over previous
//
#include <hip/hip_runtime.h>
#include <hip/hip_bf16.h>

#define NB    131072
#define EPB   8      // batch elements per block
#define NTILE 6      // M-tiles: 2 tokens x 8 elems = 16 rows
#define SEQP  12     // 11 tokens + 1 pad (pad = cls copy, finite)
#define SXW   36     // sX row stride (f32)
#define SQW2  66     // sQ row stride (u32): q/ctx raw f32 [0..31], k bf16 u16[64..95], v bf16 u16[96..127]
                     // FFN phase: h bf16 occupies u16 cols [0..127] of the same row

// ws layout (u16 units), per transformer block tb (stride WS_U16_PER_TB):
//   qkv hi @0      [6][64][8]   qkv lo @3072
//   wo  hi @6144   [2][64][8]   wo  lo @7168
//   w1  hi @8192   [8][64][8]   w1  lo @12288
//   w2  hi @16384  [4][2][64][8] w2 lo @20480
#define WS_U16_PER_TB 24576
#define WS_REQ_BYTES  (2 * WS_U16_PER_TB * 2)   // 98304 B

typedef short    bf16x8 __attribute__((ext_vector_type(8)));
typedef float    f32x4  __attribute__((ext_vector_type(4)));
typedef unsigned short u16;

struct Params {
  const float *x, *w_feat, *b_feat, *cls;
  const float *in_w[2], *in_b[2], *out_w[2], *out_b[2];
  const float *ln_a_g[2], *ln_a_b[2];
  const float *w1[2], *b1[2], *w2[2], *b2[2];
  const float *ln_b_g[2], *ln_b_b[2];
  const float *clf_w, *clf_b;
  float *out;
};

__device__ __forceinline__ float bf2f(u16 h){ return __uint_as_float(((unsigned)h)<<16); }
__device__ __forceinline__ u16 f2bf(float f){
  unsigned u = __float_as_uint(f);
  u += 0x7fffu + ((u>>16)&1u);          // RNE
  return (u16)(u>>16);
}
// truncation split: a ~= hi + lo, residual <= 2^-16 |a|
__device__ __forceinline__ void split8t(const float* p, bf16x8& hi, bf16x8& lo){
  #pragma unroll
  for (int j = 0; j < 8; ++j) {
    float a = p[j];
    unsigned u = __float_as_uint(a);
    hi[j] = (short)(u >> 16);
    float r = a - __uint_as_float(u & 0xffff0000u);
    lo[j] = (short)(__float_as_uint(r) >> 16);
  }
}
// RNE split (weights fallback path only)
__device__ __forceinline__ void split8(const float* p, bf16x8& hi, bf16x8& lo){
  #pragma unroll
  for (int j = 0; j < 8; ++j) {
    float a = p[j];
    u16 h = f2bf(a);
    hi[j] = (short)h;
    lo[j] = (short)f2bf(a - bf2f(h));
  }
}
// split-precision MFMA: acc += A*B, A=ah+al, B=bh+bl (drops al*bl ~ 2^-17)
__device__ __forceinline__ f32x4 mfma3(bf16x8 ah, bf16x8 al, bf16x8 bh, bf16x8 bl, f32x4 acc){
  acc = __builtin_amdgcn_mfma_f32_16x16x32_bf16(ah, bl, acc, 0,0,0);
  acc = __builtin_amdgcn_mfma_f32_16x16x32_bf16(al, bh, acc, 0,0,0);
  acc = __builtin_amdgcn_mfma_f32_16x16x32_bf16(ah, bh, acc, 0,0,0);
  return acc;
}
// A exact bf16, B split
__device__ __forceinline__ f32x4 mfma2(bf16x8 a, bf16x8 bh, bf16x8 bl, f32x4 acc){
  acc = __builtin_amdgcn_mfma_f32_16x16x32_bf16(a, bl, acc, 0,0,0);
  acc = __builtin_amdgcn_mfma_f32_16x16x32_bf16(a, bh, acc, 0,0,0);
  return acc;
}
__device__ __forceinline__ bf16x8 ld8(const u16* p){ return *reinterpret_cast<const bf16x8*>(p); }
// sigma-form GELU: v*sigmoid(2y) == 0.5v(1+tanh(y)) exactly (same math as tanh form, fewer ops)
__device__ __forceinline__ float gelu_fast(float v){
  float v2 = v*v;
  float t  = fmaf(0.044715f, v2, 1.0f);
  float u  = -1.5957691216057308f * v;          // -2 * 0.7978845608
  float e  = __expf(u * t);                     // exp(-2y)
  return v * __builtin_amdgcn_rcpf(1.f + e);
}
// paired RNE f32->bf16 (v_cvt_pk_bf16_f32 path)
__device__ __forceinline__ void cvt2(float a, float b, u16& oa, u16& ob){
  __hip_bfloat162 p = __float22bfloat162_rn(float2{a, b});
  oa = *reinterpret_cast<u16*>(&p.x);
  ob = *reinterpret_cast<u16*>(&p.y);
}

// ---------- prep: pre-split weights into per-lane B-fragment layout ----------
__global__ void OptimusPrime_prep(Params P, u16* ws)
{
  const int tb = blockIdx.x;
  u16* b = ws + tb * WS_U16_PER_TB;
  for (int idx = threadIdx.x; idx < 12288; idx += 256) {
    float v; int hiOff, loOff;
    if (idx < 3072) {                       // qkv  [6][64][8], K=32
      int nt = idx >> 9, lane = (idx >> 3) & 63, j = idx & 7;
      v = P.in_w[tb][(nt*16 + (lane&15))*32 + (lane>>4)*8 + j];
      hiOff = idx; loOff = 3072 + idx;
    } else if (idx < 4096) {                // wo   [2][64][8], K=32
      int m = idx - 3072;
      int nt = m >> 9, lane = (m >> 3) & 63, j = m & 7;
      v = P.out_w[tb][(nt*16 + (lane&15))*32 + (lane>>4)*8 + j];
      hiOff = 6144 + m; loOff = 7168 + m;
    } else if (idx < 8192) {                // w1   [8][64][8], K=32
      int m = idx - 4096;
      int nt = m >> 9, lane = (m >> 3) & 63, j = m & 7;
      v = P.w1[tb][(nt*16 + (lane&15))*32 + (lane>>4)*8 + j];
      hiOff = 8192 + m; loOff = 12288 + m;
    } else {                                // w2   [4][2][64][8], K=128
      int m = idx - 8192;
      int kt = m >> 10, nt = (m >> 9) & 1, lane = (m >> 3) & 63, j = m & 7;
      v = P.w2[tb][(nt*16 + (lane&15))*128 + kt*32 + (lane>>4)*8 + j];
      hiOff = 16384 + m; loOff = 20480 + m;
    }
    u16 h = f2bf(v);
    b[hiOff] = h;
    b[loOff] = f2bf(v - bf2f(h));
  }
}

// MFMA 16x16x32 bf16 layouts:
//   A-frag: a[j] = A[m=lane&15][k=(lane>>4)*8+j]
//   B-frag: b[j] = B[k=(lane>>4)*8+j][n=lane&15]
//   C/D   : acc[r] = C[row=(lane>>4)*4+r][col=lane&15]
// M-tile t covers rows m in [0,16): token s = 2t + (m>>3), elem e = m&7.

template<bool WS>
__global__ __launch_bounds__(256, 3)   // 3 waves/EU ~168 unified VGPR cap; keep every phase's live set
                                       // under ~110 regs (r7 monolith & r9 dual-qi attn both spilled GBs)
void OptimusPrime_kernel(Params P, const u16* __restrict__ ws)
{
  __shared__ float    sX[SEQP][EPB][SXW];   // 13824 B : residual stream (f32)
  __shared__ unsigned sQ[SEQP][EPB][SQW2];  // 25344 B : raw f32 q/ctx + bf16 k,v ; FFN h bf16

  const int tid  = threadIdx.x;
  const int w    = tid >> 6;
  const int lane = tid & 63;
  const int quad = lane >> 4;
  const int l16  = lane & 15;
  const int kq   = quad * 8;
  const int base = blockIdx.x * EPB;

  const int sA  = (l16 >> 3);
  const int eA  = (l16 & 7);
  const int sC  = (quad >> 1);
  const int eC0 = (quad & 1) * 4;

  // ---------- embed ----------
  for (int i = tid; i < SEQP*EPB*32; i += 256) {
    int d = i & 31, e = (i >> 5) & 7, s = i >> 8;
    float v;
    if (s == 0 || s == 11) v = P.cls[d];
    else v = P.x[(base+e)*10 + (s-1)] * P.w_feat[(s-1)*32 + d] + P.b_feat[(s-1)*32 + d];
    sX[s][e][d] = v;
  }
  __syncthreads();

  for (int tb = 0; tb < 2; ++tb) {
    const u16* wsb = WS ? (ws + tb * WS_U16_PER_TB) : nullptr;

    // ---------- P1: QKV projection ----------
    {
      bf16x8 bh[6], bl[6]; float bias[6];
      #pragma unroll
      for (int nt = 0; nt < 6; ++nt) {
        if (WS) {
          bh[nt] = ld8(wsb + (nt*64 + lane)*8);
          bl[nt] = ld8(wsb + 3072 + (nt*64 + lane)*8);
        } else {
          split8(P.in_w[tb] + (nt*16 + l16)*32 + kq, bh[nt], bl[nt]);
        }
        bias[nt] = P.in_b[tb][nt*16 + l16];
      }
      for (int t = w; t < NTILE; t += 4) {
        bf16x8 ah, al; split8t(&sX[2*t + sA][eA][kq], ah, al);
        // q (nt 0,1): raw f32
        #pragma unroll
        for (int nt = 0; nt < 2; ++nt) {
          f32x4 acc = {0.f,0.f,0.f,0.f};
          acc = mfma3(ah, al, bh[nt], bl[nt], acc);
          #pragma unroll
          for (int r = 0; r < 4; ++r)
            ((float*)&sQ[2*t + sC][eC0 + r][0])[nt*16 + l16] = acc[r] + bias[nt];
        }
        // k (nt 2,3): paired bf16 convert
        {
          f32x4 a2 = {0.f,0.f,0.f,0.f}, a3 = {0.f,0.f,0.f,0.f};
          a2 = mfma3(ah, al, bh[2], bl[2], a2);
          a3 = mfma3(ah, al, bh[3], bl[3], a3);
          #pragma unroll
          for (int r = 0; r < 4; ++r) {
            u16* row = (u16*)&sQ[2*t + sC][eC0 + r][0];
            cvt2(a2[r] + bias[2], a3[r] + bias[3], row[64 + l16], row[80 + l16]);
          }
        }
        // v (nt 4,5): paired bf16 convert
        {
          f32x4 a4 = {0.f,0.f,0.f,0.f}, a5 = {0.f,0.f,0.f,0.f};
          a4 = mfma3(ah, al, bh[4], bl[4], a4);
          a5 = mfma3(ah, al, bh[5], bl[5], a5);
          #pragma unroll
          for (int r = 0; r < 4; ++r) {
            u16* row = (u16*)&sQ[2*t + sC][eC0 + r][0];
            cvt2(a4[r] + bias[4], a5[r] + bias[5], row[96 + l16], row[112 + l16]);
          }
        }
      }
    }
    __syncthreads();

    // ---------- attention: single-qi per thread, compacted two rounds ----------
    // item ii in [0,352): qi = ii>>5, hh = (ii>>3)&3, e = ii&7
    // round 0: ii = tid (qi 0..7, all waves full)
    // round 1: ii = 256+tid, tid<96 (qi 8..10) -> waves 2,3 skip whole body via execz
    // no hazard: round 0 writes ctx only into q-rows 0..7; round 1 reads q-rows 8..10 + k/v cols
    {
      #pragma unroll
      for (int rr = 0; rr < 2; ++rr) {
        int ii = rr*256 + tid;
        if (ii < 352) {
          const int qi = ii >> 5, hh = (ii >> 3) & 3, e = ii & 7;
          const float* qp = (const float*)&sQ[qi][e][0] + hh*8;
          float qf[8];
          #pragma unroll
          for (int j = 0; j < 8; ++j) qf[j] = qp[j] * 0.35355339059f;   // 1/sqrt(8)
          float sc[11]; float l = 0.f;
          #pragma unroll
          for (int ki = 0; ki < 11; ++ki) {
            bf16x8 kv = ld8((const u16*)&sQ[ki][e][0] + 64 + hh*8);
            float s = 0.f;
            #pragma unroll
            for (int j = 0; j < 8; ++j) s = fmaf(qf[j], bf2f((u16)kv[j]), s);
            sc[ki] = __expf(s);            // scores O(1): no max-subtraction
            l += sc[ki];
          }
          float inv = __builtin_amdgcn_rcpf(l);
          float cx[8] = {0,0,0,0,0,0,0,0};
          #pragma unroll
          for (int ki = 0; ki < 11; ++ki) {
            bf16x8 vv = ld8((const u16*)&sQ[ki][e][0] + 96 + hh*8);
            float p = sc[ki];
            #pragma unroll
            for (int j = 0; j < 8; ++j) cx[j] = fmaf(p, bf2f((u16)vv[j]), cx[j]);
          }
          float* op = (float*)&sQ[qi][e][0] + hh*8;
          #pragma unroll
          for (int j = 0; j < 8; ++j) op[j] = cx[j] * inv;   // ctx -> q slot, raw f32
        }
      }
    }
    __syncthreads();

    // ---------- P3a: out-proj + LN_a (only wo live) ----------
    {
      bf16x8 woh[2], wol[2]; float ob[2], lag[2], lab[2];
      #pragma unroll
      for (int nt = 0; nt < 2; ++nt) {
        if (WS) {
          woh[nt] = ld8(wsb + 6144 + (nt*64 + lane)*8);
          wol[nt] = ld8(wsb + 7168 + (nt*64 + lane)*8);
        } else {
          split8(P.out_w[tb] + (nt*16 + l16)*32 + kq, woh[nt], wol[nt]);
        }
        ob[nt]  = P.out_b[tb][nt*16 + l16];
        lag[nt] = P.ln_a_g[tb][nt*16 + l16]; lab[nt] = P.ln_a_b[tb][nt*16 + l16];
      }
      for (int t = w; t < NTILE; t += 4) {
        bf16x8 ah, al; split8t((const float*)&sQ[2*t + sA][eA][0] + kq, ah, al);  // ctx raw f32
        float tt[2][4];
        #pragma unroll
        for (int nt = 0; nt < 2; ++nt) {
          f32x4 acc = {0.f,0.f,0.f,0.f};
          acc = mfma3(ah, al, woh[nt], wol[nt], acc);
          #pragma unroll
          for (int r = 0; r < 4; ++r)
            tt[nt][r] = acc[r] + ob[nt] + sX[2*t + sC][eC0 + r][nt*16 + l16];  // + residual
        }
        #pragma unroll
        for (int r = 0; r < 4; ++r) {
          float s1 = tt[0][r] + tt[1][r];
          float s2 = tt[0][r]*tt[0][r] + tt[1][r]*tt[1][r];
          #pragma unroll
          for (int mk = 1; mk < 16; mk <<= 1) { s1 += __shfl_xor(s1, mk); s2 += __shfl_xor(s2, mk); }
          float mu  = s1 * (1.f/32.f);
          float var = fmaxf(s2 * (1.f/32.f) - mu*mu, 0.f);
          float rs  = rsqrtf(var + 1e-5f);
          #pragma unroll
          for (int nt = 0; nt < 2; ++nt) {
            float y = (tt[nt][r] - mu)*rs*lag[nt] + lab[nt];
            sX[2*t + sC][eC0 + r][nt*16 + l16] = y;
          }
        }
      }
    }
    __builtin_amdgcn_sched_barrier(0);

    // ---------- P3b: FFN1 + GELU -> h bf16 (only w1 live) ----------
    {
      bf16x8 w1h[8], w1l[8]; float b1v[8];
      #pragma unroll
      for (int f8 = 0; f8 < 8; ++f8) {
        if (WS) {
          w1h[f8] = ld8(wsb + 8192  + (f8*64 + lane)*8);
          w1l[f8] = ld8(wsb + 12288 + (f8*64 + lane)*8);
        } else {
          split8(P.w1[tb] + (f8*16 + l16)*32 + kq, w1h[f8], w1l[f8]);
        }
        b1v[f8] = P.b1[tb][f8*16 + l16];
      }
      for (int t = w; t < NTILE; t += 4) {
        bf16x8 xh, xl; split8t(&sX[2*t + sA][eA][kq], xh, xl);
        #pragma unroll
        for (int fp = 0; fp < 4; ++fp) {
          int f0 = 2*fp, f1 = 2*fp + 1;
          f32x4 a0 = {0.f,0.f,0.f,0.f}, a1 = {0.f,0.f,0.f,0.f};
          a0 = mfma3(xh, xl, w1h[f0], w1l[f0], a0);
          a1 = mfma3(xh, xl, w1h[f1], w1l[f1], a1);
          #pragma unroll
          for (int r = 0; r < 4; ++r) {
            float g0 = gelu_fast(a0[r] + b1v[f0]);
            float g1 = gelu_fast(a1[r] + b1v[f1]);
            u16* row = (u16*)&sQ[2*t + sC][eC0 + r][0];
            cvt2(g0, g1, row[f0*16 + l16], row[f1*16 + l16]);
          }
        }
      }
    }
    __builtin_amdgcn_sched_barrier(0);

    // ---------- P3c: FFN2 + residual + LN_b (only w2 live) ----------
    {
      bf16x8 w2h[4][2], w2l[4][2]; float b2v[2], lbg[2], lbb[2];
      #pragma unroll
      for (int kt = 0; kt < 4; ++kt)
        #pragma unroll
        for (int nt = 0; nt < 2; ++nt) {
          if (WS) {
            w2h[kt][nt] = ld8(wsb + 16384 + ((kt*2 + nt)*64 + lane)*8);
            w2l[kt][nt] = ld8(wsb + 20480 + ((kt*2 + nt)*64 + lane)*8);
          } else {
            split8(P.w2[tb] + (nt*16 + l16)*128 + kt*32 + kq, w2h[kt][nt], w2l[kt][nt]);
          }
        }
      #pragma unroll
      for (int nt = 0; nt < 2; ++nt) {
        b2v[nt] = P.b2[tb][nt*16 + l16];
        lbg[nt] = P.ln_b_g[tb][nt*16 + l16]; lbb[nt] = P.ln_b_b[tb][nt*16 + l16];
      }
      for (int t = w; t < NTILE; t += 4) {
        f32x4 ca0 = {0.f,0.f,0.f,0.f}, ca1 = {0.f,0.f,0.f,0.f};
        #pragma unroll
        for (int kt = 0; kt < 4; ++kt) {
          bf16x8 hf = ld8((const u16*)&sQ[2*t + sA][eA][0] + kt*32 + kq);
          ca0 = mfma2(hf, w2h[kt][0], w2l[kt][0], ca0);
          ca1 = mfma2(hf, w2h[kt][1], w2l[kt][1], ca1);
        }
        float tt[2][4];
        #pragma unroll
        for (int nt = 0; nt < 2; ++nt) {
          f32x4 ca = nt ? ca1 : ca0;
          #pragma unroll
          for (int r = 0; r < 4; ++r)
            tt[nt][r] = ca[r] + b2v[nt] + sX[2*t + sC][eC0 + r][nt*16 + l16];  // + residual
        }
        #pragma unroll
        for (int r = 0; r < 4; ++r) {
          float s1 = tt[0][r] + tt[1][r];
          float s2 = tt[0][r]*tt[0][r] + tt[1][r]*tt[1][r];
          #pragma unroll
          for (int mk = 1; mk < 16; mk <<= 1) { s1 += __shfl_xor(s1, mk); s2 += __shfl_xor(s2, mk); }
          float mu  = s1 * (1.f/32.f);
          float var = fmaxf(s2 * (1.f/32.f) - mu*mu, 0.f);
          float rs  = rsqrtf(var + 1e-5f);
          #pragma unroll
          for (int nt = 0; nt < 2; ++nt) {
            float y = (tt[nt][r] - mu)*rs*lbg[nt] + lbb[nt];
            sX[2*t + sC][eC0 + r][nt*16 + l16] = y;
          }
        }
      }
    }
    // no end-of-layer barrier: P3c writes / next-P1 reads are same-wave same-tile LDS (in-order)
  }

  // ---------- classifier: out[b] = sX[0][e][:] . clf_w + clf_b ----------
  // sX token-0 rows are tile 0 = wave 0's P3c output (same wave, LDS in-order)
  if (w == 0) {
    int e = lane >> 3, dq = lane & 7;
    float p = 0.f;
    #pragma unroll
    for (int j = 0; j < 4; ++j)
      p += sX[0][e][dq*4 + j] * P.clf_w[dq*4 + j];
    p += __shfl_xor(p, 1);
    p += __shfl_xor(p, 2);
    p += __shfl_xor(p, 4);
    if (dq == 0)
      P.out[base + e] = p + P.clf_b[0];
  }
}

extern "C" void kernel_launch(void* const* d_in, const int* in_sizes, int n_in,
                              void* d_out, int out_size, void* d_ws, size_t ws_size,
                              hipStream_t stream)
{
  Params P;
  P.x        = (const float*)d_in[0];
  P.w_feat   = (const float*)d_in[1];
  P.b_feat   = (const float*)d_in[2];
  P.cls      = (const float*)d_in[3];
  P.in_w[0]  = (const float*)d_in[4];   P.in_b[0]  = (const float*)d_in[5];
  P.out_w[0] = (const float*)d_in[6];   P.out_b[0] = (const float*)d_in[7];
  P.ln_a_g[0]= (const float*)d_in[8];   P.ln_a_b[0]= (const float*)d_in[9];
  P.w1[0]    = (const float*)d_in[10];  P.b1[0]    = (const float*)d_in[11];
  P.w2[0]    = (const float*)d_in[12];  P.b2[0]    = (const float*)d_in[13];
  P.ln_b_g[0]= (const float*)d_in[14];  P.ln_b_b[0]= (const float*)d_in[15];
  P.in_w[1]  = (const float*)d_in[16];  P.in_b[1]  = (const float*)d_in[17];
  P.out_w[1] = (const float*)d_in[18];  P.out_b[1] = (const float*)d_in[19];
  P.ln_a_g[1]= (const float*)d_in[20];  P.ln_a_b[1]= (const float*)d_in[21];
  P.w1[1]    = (const float*)d_in[22];  P.b1[1]    = (const float*)d_in[23];
  P.w2[1]    = (const float*)d_in[24];  P.b2[1]    = (const float*)d_in[25];
  P.ln_b_g[1]= (const float*)d_in[26];  P.ln_b_b[1]= (const float*)d_in[27];
  P.clf_w    = (const float*)d_in[28];  P.clf_b    = (const float*)d_in[29];
  P.out      = (float*)d_out;

  dim3 grid(NB / EPB), block(256);
  if (ws_size >= (size_t)WS_REQ_BYTES) {
    u16* ws = (u16*)d_ws;
    hipLaunchKernelGGL(OptimusPrime_prep, dim3(2), dim3(256), 0, stream, P, ws);
    hipLaunchKernelGGL(OptimusPrime_kernel<true>, grid, block, 0, stream, P, (const u16*)ws);
  } else {
    hipLaunchKernelGGL(OptimusPrime_kernel<false>, grid, block, 0, stream, P, (const u16*)nullptr);
  }
}

// Round 11
// 951.429 us; speedup vs baseline: 1.4816x; 1.0465x over previous
//
#include <hip/hip_runtime.h>
#include <hip/hip_bf16.h>

#define NB    131072
#define EPB   8      // batch elements per block
#define NTILE 6      // M-tiles: 2 tokens x 8 elems = 16 rows
#define SEQP  12     // 11 tokens + 1 pad (pad = cls copy, finite)
#define SXW   36     // sX row stride (f32)
#define SQW2  66     // sQ row stride (u32): q/ctx raw f32 [0..31], k bf16 u16[64..95], v bf16 u16[96..127]
                     // FFN phase: h bf16 occupies u16 cols [0..127] of the same row

// ws layout (u16 units), per transformer block tb (stride WS_U16_PER_TB):
//   qkv hi @0      [6][64][8]   qkv lo @3072
//   wo  hi @6144   [2][64][8]   wo  lo @7168
//   w1  hi @8192   [8][64][8]   w1  lo @12288
//   w2  hi @16384  [4][2][64][8] w2 lo @20480
#define WS_U16_PER_TB 24576
#define WS_REQ_BYTES  (2 * WS_U16_PER_TB * 2)   // 98304 B

typedef short    bf16x8 __attribute__((ext_vector_type(8)));
typedef float    f32x4  __attribute__((ext_vector_type(4)));
typedef unsigned short u16;

struct Params {
  const float *x, *w_feat, *b_feat, *cls;
  const float *in_w[2], *in_b[2], *out_w[2], *out_b[2];
  const float *ln_a_g[2], *ln_a_b[2];
  const float *w1[2], *b1[2], *w2[2], *b2[2];
  const float *ln_b_g[2], *ln_b_b[2];
  const float *clf_w, *clf_b;
  float *out;
};

__device__ __forceinline__ float bf2f(u16 h){ return __uint_as_float(((unsigned)h)<<16); }
__device__ __forceinline__ u16 f2bf(float f){
  unsigned u = __float_as_uint(f);
  u += 0x7fffu + ((u>>16)&1u);          // RNE
  return (u16)(u>>16);
}
// truncation split: a ~= hi + lo, residual <= 2^-16 |a|
__device__ __forceinline__ void split8t(const float* p, bf16x8& hi, bf16x8& lo){
  #pragma unroll
  for (int j = 0; j < 8; ++j) {
    float a = p[j];
    unsigned u = __float_as_uint(a);
    hi[j] = (short)(u >> 16);
    float r = a - __uint_as_float(u & 0xffff0000u);
    lo[j] = (short)(__float_as_uint(r) >> 16);
  }
}
// RNE split (weights fallback path only)
__device__ __forceinline__ void split8(const float* p, bf16x8& hi, bf16x8& lo){
  #pragma unroll
  for (int j = 0; j < 8; ++j) {
    float a = p[j];
    u16 h = f2bf(a);
    hi[j] = (short)h;
    lo[j] = (short)f2bf(a - bf2f(h));
  }
}
// split-precision MFMA: acc += A*B, A=ah+al, B=bh+bl (drops al*bl ~ 2^-17)
__device__ __forceinline__ f32x4 mfma3(bf16x8 ah, bf16x8 al, bf16x8 bh, bf16x8 bl, f32x4 acc){
  acc = __builtin_amdgcn_mfma_f32_16x16x32_bf16(ah, bl, acc, 0,0,0);
  acc = __builtin_amdgcn_mfma_f32_16x16x32_bf16(al, bh, acc, 0,0,0);
  acc = __builtin_amdgcn_mfma_f32_16x16x32_bf16(ah, bh, acc, 0,0,0);
  return acc;
}
// A exact bf16, B split
__device__ __forceinline__ f32x4 mfma2(bf16x8 a, bf16x8 bh, bf16x8 bl, f32x4 acc){
  acc = __builtin_amdgcn_mfma_f32_16x16x32_bf16(a, bl, acc, 0,0,0);
  acc = __builtin_amdgcn_mfma_f32_16x16x32_bf16(a, bh, acc, 0,0,0);
  return acc;
}
__device__ __forceinline__ bf16x8 ld8(const u16* p){ return *reinterpret_cast<const bf16x8*>(p); }
// sigma-form GELU: v*sigmoid(2y) == 0.5v(1+tanh(y)) exactly
__device__ __forceinline__ float gelu_fast(float v){
  float v2 = v*v;
  float t  = fmaf(0.044715f, v2, 1.0f);
  float u  = -1.5957691216057308f * v;          // -2 * 0.7978845608
  float e  = __expf(u * t);                     // exp(-2y)
  return v * __builtin_amdgcn_rcpf(1.f + e);
}
// paired RNE f32->bf16 (v_cvt_pk_bf16_f32 path)
__device__ __forceinline__ void cvt2(float a, float b, u16& oa, u16& ob){
  __hip_bfloat162 p = __float22bfloat162_rn(float2{a, b});
  oa = *reinterpret_cast<u16*>(&p.x);
  ob = *reinterpret_cast<u16*>(&p.y);
}

// ---------- prep: pre-split weights into per-lane B-fragment layout ----------
__global__ void OptimusPrime_prep(Params P, u16* ws)
{
  const int tb = blockIdx.x;
  u16* b = ws + tb * WS_U16_PER_TB;
  for (int idx = threadIdx.x; idx < 12288; idx += 256) {
    float v; int hiOff, loOff;
    if (idx < 3072) {                       // qkv  [6][64][8], K=32
      int nt = idx >> 9, lane = (idx >> 3) & 63, j = idx & 7;
      v = P.in_w[tb][(nt*16 + (lane&15))*32 + (lane>>4)*8 + j];
      hiOff = idx; loOff = 3072 + idx;
    } else if (idx < 4096) {                // wo   [2][64][8], K=32
      int m = idx - 3072;
      int nt = m >> 9, lane = (m >> 3) & 63, j = m & 7;
      v = P.out_w[tb][(nt*16 + (lane&15))*32 + (lane>>4)*8 + j];
      hiOff = 6144 + m; loOff = 7168 + m;
    } else if (idx < 8192) {                // w1   [8][64][8], K=32
      int m = idx - 4096;
      int nt = m >> 9, lane = (m >> 3) & 63, j = m & 7;
      v = P.w1[tb][(nt*16 + (lane&15))*32 + (lane>>4)*8 + j];
      hiOff = 8192 + m; loOff = 12288 + m;
    } else {                                // w2   [4][2][64][8], K=128
      int m = idx - 8192;
      int kt = m >> 10, nt = (m >> 9) & 1, lane = (m >> 3) & 63, j = m & 7;
      v = P.w2[tb][(nt*16 + (lane&15))*128 + kt*32 + (lane>>4)*8 + j];
      hiOff = 16384 + m; loOff = 20480 + m;
    }
    u16 h = f2bf(v);
    b[hiOff] = h;
    b[loOff] = f2bf(v - bf2f(h));
  }
}

// MFMA 16x16x32 bf16 layouts:
//   A-frag: a[j] = A[m=lane&15][k=(lane>>4)*8+j]
//   B-frag: b[j] = B[k=(lane>>4)*8+j][n=lane&15]
//   C/D   : acc[r] = C[row=(lane>>4)*4+r][col=lane&15]
// M-tile t covers rows m in [0,16): token s = 2t + (m>>3), elem e = m&7.

template<bool WS>
__global__ __launch_bounds__(256, 4)   // 4 waves/EU = 64-VGPR cap, 4 blocks/CU (LDS 4x39424=157.7K fits;
                                       // r6 proved 4 blocks resident). Every phase's live set kept <~55 regs:
                                       // online-softmax attn (no sc[11]), P3b split halves, P3c per-kt w2 loads.
void OptimusPrime_kernel(Params P, const u16* __restrict__ ws)
{
  __shared__ float    sX[SEQP][EPB][SXW];   // 13824 B : residual stream (f32)
  __shared__ unsigned sQ[SEQP][EPB][SQW2];  // 25344 B : raw f32 q/ctx + bf16 k,v ; FFN h bf16

  const int tid  = threadIdx.x;
  const int w    = tid >> 6;
  const int lane = tid & 63;
  const int quad = lane >> 4;
  const int l16  = lane & 15;
  const int kq   = quad * 8;
  const int base = blockIdx.x * EPB;

  const int sA  = (l16 >> 3);
  const int eA  = (l16 & 7);
  const int sC  = (quad >> 1);
  const int eC0 = (quad & 1) * 4;

  // ---------- embed ----------
  for (int i = tid; i < SEQP*EPB*32; i += 256) {
    int d = i & 31, e = (i >> 5) & 7, s = i >> 8;
    float v;
    if (s == 0 || s == 11) v = P.cls[d];
    else v = P.x[(base+e)*10 + (s-1)] * P.w_feat[(s-1)*32 + d] + P.b_feat[(s-1)*32 + d];
    sX[s][e][d] = v;
  }
  __syncthreads();

  for (int tb = 0; tb < 2; ++tb) {
    const u16* wsb = WS ? (ws + tb * WS_U16_PER_TB) : nullptr;

    // ---------- P1: QKV projection (q pre-scaled by 1/sqrt(8)) ----------
    {
      bf16x8 bh[6], bl[6]; float bias[6];
      #pragma unroll
      for (int nt = 0; nt < 6; ++nt) {
        if (WS) {
          bh[nt] = ld8(wsb + (nt*64 + lane)*8);
          bl[nt] = ld8(wsb + 3072 + (nt*64 + lane)*8);
        } else {
          split8(P.in_w[tb] + (nt*16 + l16)*32 + kq, bh[nt], bl[nt]);
        }
        bias[nt] = P.in_b[tb][nt*16 + l16];
      }
      for (int t = w; t < NTILE; t += 4) {
        bf16x8 ah, al; split8t(&sX[2*t + sA][eA][kq], ah, al);
        // q (nt 0,1): raw f32, pre-scaled
        #pragma unroll
        for (int nt = 0; nt < 2; ++nt) {
          f32x4 acc = {0.f,0.f,0.f,0.f};
          acc = mfma3(ah, al, bh[nt], bl[nt], acc);
          #pragma unroll
          for (int r = 0; r < 4; ++r)
            ((float*)&sQ[2*t + sC][eC0 + r][0])[nt*16 + l16] = (acc[r] + bias[nt]) * 0.35355339059f;
        }
        // k (nt 2,3): paired bf16 convert
        {
          f32x4 a2 = {0.f,0.f,0.f,0.f}, a3 = {0.f,0.f,0.f,0.f};
          a2 = mfma3(ah, al, bh[2], bl[2], a2);
          a3 = mfma3(ah, al, bh[3], bl[3], a3);
          #pragma unroll
          for (int r = 0; r < 4; ++r) {
            u16* row = (u16*)&sQ[2*t + sC][eC0 + r][0];
            cvt2(a2[r] + bias[2], a3[r] + bias[3], row[64 + l16], row[80 + l16]);
          }
        }
        // v (nt 4,5): paired bf16 convert
        {
          f32x4 a4 = {0.f,0.f,0.f,0.f}, a5 = {0.f,0.f,0.f,0.f};
          a4 = mfma3(ah, al, bh[4], bl[4], a4);
          a5 = mfma3(ah, al, bh[5], bl[5], a5);
          #pragma unroll
          for (int r = 0; r < 4; ++r) {
            u16* row = (u16*)&sQ[2*t + sC][eC0 + r][0];
            cvt2(a4[r] + bias[4], a5[r] + bias[5], row[96 + l16], row[112 + l16]);
          }
        }
      }
    }
    __syncthreads();

    // ---------- attention: online softmax, single k/v pass, compacted two rounds ----------
    // item ii in [0,352): qi = ii>>5, hh = (ii>>3)&3, e = ii&7
    // round 0: ii = tid (qi 0..7); round 1: ii = 256+tid for tid<96 (qi 8..10; waves 2,3 skip via execz)
    // no hazard: round 0 writes ctx only into q-rows 0..7; round 1 reads q-rows 8..10 + k/v cols
    {
      for (int rr = 0; rr < 2; ++rr) {
        int ii = rr*256 + tid;
        if (ii < 352) {
          const int qi = ii >> 5, hh = (ii >> 3) & 3, e = ii & 7;
          const float* qp = (const float*)&sQ[qi][e][0] + hh*8;
          float qf[8];
          #pragma unroll
          for (int j = 0; j < 8; ++j) qf[j] = qp[j];     // already scaled in P1
          float l = 0.f, cx[8] = {0,0,0,0,0,0,0,0};
          for (int ki = 0; ki < 11; ++ki) {
            const u16* row = (const u16*)&sQ[ki][e][0];
            bf16x8 kv = ld8(row + 64 + hh*8);
            float s = 0.f;
            #pragma unroll
            for (int j = 0; j < 8; ++j) s = fmaf(qf[j], bf2f((u16)kv[j]), s);
            float p = __expf(s);                          // scores O(1): no max-subtraction
            l += p;
            bf16x8 vv = ld8(row + 96 + hh*8);
            #pragma unroll
            for (int j = 0; j < 8; ++j) cx[j] = fmaf(p, bf2f((u16)vv[j]), cx[j]);
          }
          float inv = __builtin_amdgcn_rcpf(l);
          float* op = (float*)&sQ[qi][e][0] + hh*8;
          #pragma unroll
          for (int j = 0; j < 8; ++j) op[j] = cx[j] * inv;   // ctx -> q slot, raw f32
        }
      }
    }
    __syncthreads();

    // ---------- P3a: out-proj + LN_a (only wo live) ----------
    {
      bf16x8 woh[2], wol[2]; float ob[2], lag[2], lab[2];
      #pragma unroll
      for (int nt = 0; nt < 2; ++nt) {
        if (WS) {
          woh[nt] = ld8(wsb + 6144 + (nt*64 + lane)*8);
          wol[nt] = ld8(wsb + 7168 + (nt*64 + lane)*8);
        } else {
          split8(P.out_w[tb] + (nt*16 + l16)*32 + kq, woh[nt], wol[nt]);
        }
        ob[nt]  = P.out_b[tb][nt*16 + l16];
        lag[nt] = P.ln_a_g[tb][nt*16 + l16]; lab[nt] = P.ln_a_b[tb][nt*16 + l16];
      }
      for (int t = w; t < NTILE; t += 4) {
        bf16x8 ah, al; split8t((const float*)&sQ[2*t + sA][eA][0] + kq, ah, al);  // ctx raw f32
        float tt[2][4];
        #pragma unroll
        for (int nt = 0; nt < 2; ++nt) {
          f32x4 acc = {0.f,0.f,0.f,0.f};
          acc = mfma3(ah, al, woh[nt], wol[nt], acc);
          #pragma unroll
          for (int r = 0; r < 4; ++r)
            tt[nt][r] = acc[r] + ob[nt] + sX[2*t + sC][eC0 + r][nt*16 + l16];  // + residual
        }
        #pragma unroll
        for (int r = 0; r < 4; ++r) {
          float s1 = tt[0][r] + tt[1][r];
          float s2 = tt[0][r]*tt[0][r] + tt[1][r]*tt[1][r];
          #pragma unroll
          for (int mk = 1; mk < 16; mk <<= 1) { s1 += __shfl_xor(s1, mk); s2 += __shfl_xor(s2, mk); }
          float mu  = s1 * (1.f/32.f);
          float var = fmaxf(s2 * (1.f/32.f) - mu*mu, 0.f);
          float rs  = rsqrtf(var + 1e-5f);
          #pragma unroll
          for (int nt = 0; nt < 2; ++nt) {
            float y = (tt[nt][r] - mu)*rs*lag[nt] + lab[nt];
            sX[2*t + sC][eC0 + r][nt*16 + l16] = y;
          }
        }
      }
    }
    __builtin_amdgcn_sched_barrier(0);

    // ---------- P3b: FFN1 + GELU -> h bf16, two feature halves (w1 live = 4 frag pairs) ----------
    {
      #pragma unroll
      for (int hf = 0; hf < 2; ++hf) {
        bf16x8 w1h[4], w1l[4]; float b1v[4];
        #pragma unroll
        for (int i4 = 0; i4 < 4; ++i4) {
          int f8 = hf*4 + i4;
          if (WS) {
            w1h[i4] = ld8(wsb + 8192  + (f8*64 + lane)*8);
            w1l[i4] = ld8(wsb + 12288 + (f8*64 + lane)*8);
          } else {
            split8(P.w1[tb] + (f8*16 + l16)*32 + kq, w1h[i4], w1l[i4]);
          }
          b1v[i4] = P.b1[tb][f8*16 + l16];
        }
        for (int t = w; t < NTILE; t += 4) {
          bf16x8 xh, xl; split8t(&sX[2*t + sA][eA][kq], xh, xl);
          #pragma unroll
          for (int fp = 0; fp < 2; ++fp) {
            int i0 = 2*fp, i1 = 2*fp + 1;
            f32x4 a0 = {0.f,0.f,0.f,0.f}, a1 = {0.f,0.f,0.f,0.f};
            a0 = mfma3(xh, xl, w1h[i0], w1l[i0], a0);
            a1 = mfma3(xh, xl, w1h[i1], w1l[i1], a1);
            int f0 = hf*4 + i0, f1 = hf*4 + i1;
            #pragma unroll
            for (int r = 0; r < 4; ++r) {
              float g0 = gelu_fast(a0[r] + b1v[i0]);
              float g1 = gelu_fast(a1[r] + b1v[i1]);
              u16* row = (u16*)&sQ[2*t + sC][eC0 + r][0];
              cvt2(g0, g1, row[f0*16 + l16], row[f1*16 + l16]);
            }
          }
        }
        __builtin_amdgcn_sched_barrier(0);
      }
    }

    // ---------- P3c: FFN2 + residual + LN_b (w2 loaded per-kt: 2 frag pairs live) ----------
    {
      float b2v[2], lbg[2], lbb[2];
      #pragma unroll
      for (int nt = 0; nt < 2; ++nt) {
        b2v[nt] = P.b2[tb][nt*16 + l16];
        lbg[nt] = P.ln_b_g[tb][nt*16 + l16]; lbb[nt] = P.ln_b_b[tb][nt*16 + l16];
      }
      for (int t = w; t < NTILE; t += 4) {
        f32x4 ca0 = {0.f,0.f,0.f,0.f}, ca1 = {0.f,0.f,0.f,0.f};
        #pragma unroll
        for (int kt = 0; kt < 4; ++kt) {
          bf16x8 hf = ld8((const u16*)&sQ[2*t + sA][eA][0] + kt*32 + kq);
          bf16x8 wh0, wl0, wh1, wl1;
          if (WS) {
            wh0 = ld8(wsb + 16384 + ((kt*2 + 0)*64 + lane)*8);
            wl0 = ld8(wsb + 20480 + ((kt*2 + 0)*64 + lane)*8);
            wh1 = ld8(wsb + 16384 + ((kt*2 + 1)*64 + lane)*8);
            wl1 = ld8(wsb + 20480 + ((kt*2 + 1)*64 + lane)*8);
          } else {
            split8(P.w2[tb] + (0*16 + l16)*128 + kt*32 + kq, wh0, wl0);
            split8(P.w2[tb] + (1*16 + l16)*128 + kt*32 + kq, wh1, wl1);
          }
          ca0 = mfma2(hf, wh0, wl0, ca0);
          ca1 = mfma2(hf, wh1, wl1, ca1);
        }
        float tt[2][4];
        #pragma unroll
        for (int nt = 0; nt < 2; ++nt) {
          f32x4 ca = nt ? ca1 : ca0;
          #pragma unroll
          for (int r = 0; r < 4; ++r)
            tt[nt][r] = ca[r] + b2v[nt] + sX[2*t + sC][eC0 + r][nt*16 + l16];  // + residual
        }
        #pragma unroll
        for (int r = 0; r < 4; ++r) {
          float s1 = tt[0][r] + tt[1][r];
          float s2 = tt[0][r]*tt[0][r] + tt[1][r]*tt[1][r];
          #pragma unroll
          for (int mk = 1; mk < 16; mk <<= 1) { s1 += __shfl_xor(s1, mk); s2 += __shfl_xor(s2, mk); }
          float mu  = s1 * (1.f/32.f);
          float var = fmaxf(s2 * (1.f/32.f) - mu*mu, 0.f);
          float rs  = rsqrtf(var + 1e-5f);
          #pragma unroll
          for (int nt = 0; nt < 2; ++nt) {
            float y = (tt[nt][r] - mu)*rs*lbg[nt] + lbb[nt];
            sX[2*t + sC][eC0 + r][nt*16 + l16] = y;
          }
        }
      }
    }
    // no end-of-layer barrier: P3c writes / next-P1 reads are same-wave same-tile LDS (in-order)
  }

  // ---------- classifier: out[b] = sX[0][e][:] . clf_w + clf_b ----------
  if (w == 0) {
    int e = lane >> 3, dq = lane & 7;
    float p = 0.f;
    #pragma unroll
    for (int j = 0; j < 4; ++j)
      p += sX[0][e][dq*4 + j] * P.clf_w[dq*4 + j];
    p += __shfl_xor(p, 1);
    p += __shfl_xor(p, 2);
    p += __shfl_xor(p, 4);
    if (dq == 0)
      P.out[base + e] = p + P.clf_b[0];
  }
}

extern "C" void kernel_launch(void* const* d_in, const int* in_sizes, int n_in,
                              void* d_out, int out_size, void* d_ws, size_t ws_size,
                              hipStream_t stream)
{
  Params P;
  P.x        = (const float*)d_in[0];
  P.w_feat   = (const float*)d_in[1];
  P.b_feat   = (const float*)d_in[2];
  P.cls      = (const float*)d_in[3];
  P.in_w[0]  = (const float*)d_in[4];   P.in_b[0]  = (const float*)d_in[5];
  P.out_w[0] = (const float*)d_in[6];   P.out_b[0] = (const float*)d_in[7];
  P.ln_a_g[0]= (const float*)d_in[8];   P.ln_a_b[0]= (const float*)d_in[9];
  P.w1[0]    = (const float*)d_in[10];  P.b1[0]    = (const float*)d_in[11];
  P.w2[0]    = (const float*)d_in[12];  P.b2[0]    = (const float*)d_in[13];
  P.ln_b_g[0]= (const float*)d_in[14];  P.ln_b_b[0]= (const float*)d_in[15];
  P.in_w[1]  = (const float*)d_in[16];  P.in_b[1]  = (const float*)d_in[17];
  P.out_w[1] = (const float*)d_in[18];  P.out_b[1] = (const float*)d_in[19];
  P.ln_a_g[1]= (const float*)d_in[20];  P.ln_a_b[1]= (const float*)d_in[21];
  P.w1[1]    = (const float*)d_in[22];  P.b1[1]    = (const float*)d_in[23];
  P.w2[1]    = (const float*)d_in[24];  P.b2[1]    = (const float*)d_in[25];
  P.ln_b_g[1]= (const float*)d_in[26];  P.ln_b_b[1]= (const float*)d_in[27];
  P.clf_w    = (const float*)d_in[28];  P.clf_b    = (const float*)d_in[29];
  P.out      = (float*)d_out;

  dim3 grid(NB / EPB), block(256);
  if (ws_size >= (size_t)WS_REQ_BYTES) {
    u16* ws = (u16*)d_ws;
    hipLaunchKernelGGL(OptimusPrime_prep, dim3(2), dim3(256), 0, stream, P, ws);
    hipLaunchKernelGGL(OptimusPrime_kernel<true>, grid, block, 0, stream, P, (const u16*)ws);
  } else {
    hipLaunchKernelGGL(OptimusPrime_kernel<false>, grid, block, 0, stream, P, (const u16*)nullptr);
  }
}